// Round 18
// baseline (43.252 us; speedup 1.0000x reference)
//
#include <hip/hip_runtime.h>
#include <hip/hip_bf16.h>
#include <climits>

typedef __bf16 bf16;
typedef __bf16 bf16x4 __attribute__((ext_vector_type(4)));
typedef __bf16 bf16x8 __attribute__((ext_vector_type(8)));
typedef float f32x4 __attribute__((ext_vector_type(4)));

#define NB 8
#define L_ 4096
#define C_ 512
#define KW 5
#define NS 8
#define BM 64

#define BARRIER_MEM                                                            \
  do {                                                                         \
    __builtin_amdgcn_sched_barrier(0);                                         \
    __builtin_amdgcn_s_barrier();                                              \
    __builtin_amdgcn_sched_barrier(0);                                         \
  } while (0)
#define DSFLUSH_BARRIER                                                        \
  do {                                                                         \
    asm volatile("s_waitcnt lgkmcnt(0)" ::: "memory");                         \
    BARRIER_MEM;                                                               \
  } while (0)

// ---------------------------------------------------------------------------
// prep (merged): blocks 0..127 pack w_pw -> bf16 MFMA B-frag order;
//                blocks 128..639 compute bias2[n] = b_pw[n] + w_pw[n,:].b_dw
// ---------------------------------------------------------------------------
__global__ __launch_bounds__(256) void prep_kernel(
    const float* __restrict__ w_pw, const float* __restrict__ b_dw,
    const float* __restrict__ b_pw, bf16* __restrict__ pk,
    float* __restrict__ bias2) {
  const int t = threadIdx.x;
  if (blockIdx.x < 128) {
    const int gid = blockIdx.x * 256 + t;  // 0..32767
    const int lane = gid & 63;
    const int nf = (gid >> 6) & 3;
    const int wnn = (gid >> 8) & 7;
    const int kk = gid >> 11;
    const int n = wnn * 64 + nf * 16 + (lane & 15);
    const int c = kk * 32 + (lane >> 4) * 8;
    const float* s = w_pw + n * C_ + c;
    float4 a = *(const float4*)s;
    float4 b4 = *(const float4*)(s + 4);
    bf16x8 h;
    h[0] = (bf16)a.x; h[1] = (bf16)a.y; h[2] = (bf16)a.z; h[3] = (bf16)a.w;
    h[4] = (bf16)b4.x; h[5] = (bf16)b4.y; h[6] = (bf16)b4.z; h[7] = (bf16)b4.w;
    *(bf16x8*)(pk + (size_t)gid * 8) = h;
  } else {
    const int n = blockIdx.x - 128;  // 0..511
    float2 v = *(const float2*)(w_pw + n * C_ + 2 * t);
    float2 bb = *(const float2*)(b_dw + 2 * t);
    float s = v.x * bb.x + v.y * bb.y;
#pragma unroll
    for (int off = 32; off; off >>= 1) s += __shfl_down(s, off, 64);
    __shared__ float part[4];
    if ((t & 63) == 0) part[t >> 6] = s;
    __syncthreads();
    if (t == 0) bias2[n] = b_pw[n] + part[0] + part[1] + part[2] + part[3];
  }
}

// ---------------------------------------------------------------------------
// fused, single-generation (1 block/CU), two 64-row tiles per block:
//  P0: conv(t0) -> As[0] (R14 3-deep register rolling window) | lgkm barrier
//  P1 (fused, no barriers): 4 supersteps of
//      { issue t1 x-loads (next group) ; conv-compute t1 group -> As[1] ;
//        4 GEMM K-steps on As[0] }  -- MFMA hides x-latency + conv VALU
//  epilogue(t0)  | lgkm barrier
//  P2: GEMM(t1) on As[1]; epilogue(t1).
// Grid: 256 blocks x 512 thr (8 waves, 2/SIMD, 256-VGPR budget), LDS 128 KB.
// ---------------------------------------------------------------------------
__global__ __launch_bounds__(512, 2) void fused_kernel(
    const float* __restrict__ x, const int* __restrict__ segb,
    const float* __restrict__ w_dw, const bf16* __restrict__ pk,
    const float* __restrict__ bias2, float* __restrict__ out) {
  __shared__ __align__(16) bf16 As[2][BM * C_];  // 128 KB

  const int t = threadIdx.x;
  const int lane = t & 63;
  const int b = blockIdx.x >> 5;          // 32 blocks per batch row
  const int l0 = (blockIdx.x & 31) << 7;  // 128-row base

  const f32x4 z4 = (f32x4){0.f, 0.f, 0.f, 0.f};
  const int q = t & 127;         // channel quad (4 ch)
  const int r0 = (t >> 7) << 4;  // strip base 0/16/32/48 (tile-local)

  // ---- conv constants
  float4 raw[5];
#pragma unroll
  for (int i = 0; i < 5; ++i)
    raw[i] = *(const float4*)(w_dw + q * 20 + i * 4);
  f32x4 wt[5];
#pragma unroll
  for (int m = 0; m < 5; ++m)
#pragma unroll
    for (int i = 0; i < 4; ++i) {
      const int f = i * 5 + m;
      wt[m][i] = ((const float*)&raw[f >> 2])[f & 3];
    }
  const int* sb = segb + b * NS * 2;
  int stv[NS];
#pragma unroll
  for (int s = 0; s < NS; ++s) stv[s] = sb[2 * s];
  auto nxt = [&](int l) {
    int nn = INT_MAX;
#pragma unroll
    for (int s = 0; s < NS; ++s)
      nn = (stv[s] > l && stv[s] < nn) ? stv[s] : nn;
    return nn;
  };

  f32x4 w0 = z4, w1 = z4, w2 = z4, w3 = z4;
  int ns = 0;

  auto dorow = [&](bf16* dst, int l, f32x4& A, f32x4& B4, f32x4& Cc, f32x4& D,
                   const f32x4& E, int rloc) {
    if (l == ns) { A = z4; B4 = z4; Cc = z4; D = z4; ns = nxt(l); }
    f32x4 r;
#pragma unroll
    for (int i = 0; i < 4; ++i) {
      float a = A[i] * wt[0][i];
      a = fmaf(B4[i], wt[1][i], a);
      a = fmaf(Cc[i], wt[2][i], a);
      a = fmaf(D[i], wt[3][i], a);
      a = fmaf(E[i], wt[4][i], a);
      r[i] = a;
    }
    bf16x4 h;
#pragma unroll
    for (int i = 0; i < 4; ++i) h[i] = (bf16)r[i];
    const int u = q ^ ((rloc & 7) << 1);  // quad-unit XOR swizzle
    *(bf16x4*)&dst[rloc * 512 + u * 4] = h;
  };

  // ================= P0: conv(t0) -> As[0] =================
  {
    ns = nxt(l0 + r0 - 4);
    const float* gxb = x + (size_t)(b * L_ + l0 + r0) * C_ + q * 4;
    f32x4 p0[4], p1[4], p2[4];
    auto ldg = [&](int g, f32x4 (&p)[4]) {
#pragma unroll
      for (int j = 0; j < 4; ++j)
        p[j] = *(const f32x4*)(gxb + (ptrdiff_t)(g * 4 + j) * C_);
    };
    ldg(0, p0);
    ldg(1, p1);
    ldg(2, p2);
#pragma unroll
    for (int i = 0; i < 4; ++i) {
      const int l = l0 + r0 - 4 + i;
      f32x4 nv = z4;
      if (l >= 0) nv = *(const f32x4*)(gxb + (ptrdiff_t)(i - 4) * C_);
      if (l == ns) { w0 = z4; w1 = z4; w2 = z4; w3 = z4; ns = nxt(l); }
      w0 = w1; w1 = w2; w2 = w3; w3 = nv;
    }
    auto compute = [&](int g, f32x4 (&p)[4]) {
      const int lb = l0 + r0 + g * 4;
      const int rl = r0 + g * 4;
      dorow((bf16*)As[0], lb + 0, w0, w1, w2, w3, p[0], rl + 0);
      dorow((bf16*)As[0], lb + 1, w1, w2, w3, p[0], p[1], rl + 1);
      dorow((bf16*)As[0], lb + 2, w2, w3, p[0], p[1], p[2], rl + 2);
      dorow((bf16*)As[0], lb + 3, w3, p[0], p[1], p[2], p[3], rl + 3);
      w0 = p[0]; w1 = p[1]; w2 = p[2]; w3 = p[3];
    };
    compute(0, p0);
    ldg(3, p0);
    compute(1, p1);
    compute(2, p2);
    compute(3, p0);
  }
  DSFLUSH_BARRIER;  // As[0] published

  // ---- GEMM machinery (shared by both tiles)
  const int wn = t >> 6;     // 0..7
  const int cg = lane >> 4;  // k-chunk group
  const int rx = lane & 7;
  int aRow[4];
#pragma unroll
  for (int mf = 0; mf < 4; ++mf) aRow[mf] = (mf * 16 + (lane & 15)) * 512;
  const bf16* pw = pk + (size_t)wn * 2048 + lane * 8;

  f32x4 acc[4][4];
#pragma unroll
  for (int i = 0; i < 4; ++i)
#pragma unroll
    for (int j = 0; j < 4; ++j) acc[i][j] = z4;

  auto gemm_step = [&](const bf16* Ab, int kk) {
    const bf16* pws = pw + kk * 16384;
    bf16x8 bb[4];
#pragma unroll
    for (int nf = 0; nf < 4; ++nf)
      bb[nf] = *(const bf16x8*)(pws + nf * 512);
    const int ao = ((kk * 4 + cg) ^ rx) << 3;
    bf16x8 af[4];
#pragma unroll
    for (int mf = 0; mf < 4; ++mf)
      af[mf] = *(const bf16x8*)&Ab[aRow[mf] + ao];
    __builtin_amdgcn_s_setprio(1);
#pragma unroll
    for (int nf = 0; nf < 4; ++nf)
#pragma unroll
      for (int mf = 0; mf < 4; ++mf)
        acc[mf][nf] = __builtin_amdgcn_mfma_f32_16x16x32_bf16(
            af[mf], bb[nf], acc[mf][nf], 0, 0, 0);
    __builtin_amdgcn_s_setprio(0);
  };

  auto epilogue = [&](int tileOff) {
    const int col0 = wn * 64 + (lane & 15);
    float bia[4];
#pragma unroll
    for (int nf = 0; nf < 4; ++nf) bia[nf] = bias2[col0 + nf * 16];
    const int rb0 = l0 + tileOff + (cg << 2);
#pragma unroll
    for (int mf = 0; mf < 4; ++mf) {
#pragma unroll
      for (int i = 0; i < 4; ++i) {
        const int row = rb0 + mf * 16 + i;
        float* o = out + (size_t)(b * L_ + row) * C_ + col0;
#pragma unroll
        for (int nf = 0; nf < 4; ++nf) o[nf * 16] = acc[mf][nf][i] + bia[nf];
      }
    }
  };

  // ================= P1: GEMM(t0) interleaved with conv(t1) =================
  {
    ns = nxt(l0 + 64 + r0 - 4);
    const float* gxb1 = x + (size_t)(b * L_ + l0 + 64 + r0) * C_ + q * 4;
    f32x4 pA[4], pB[4];
    auto ldg1 = [&](int g, f32x4 (&p)[4]) {
#pragma unroll
      for (int j = 0; j < 4; ++j)
        p[j] = *(const f32x4*)(gxb1 + (ptrdiff_t)(g * 4 + j) * C_);
    };
    // warmup (rows l0+64+r0-4.. : always >= 60, no clamp)
    {
      f32x4 hw[4];
#pragma unroll
      for (int i = 0; i < 4; ++i)
        hw[i] = *(const f32x4*)(gxb1 + (ptrdiff_t)(i - 4) * C_);
      ldg1(0, pA);
      w0 = z4; w1 = z4; w2 = z4; w3 = z4;
#pragma unroll
      for (int i = 0; i < 4; ++i) {
        const int l = l0 + 64 + r0 - 4 + i;
        if (l == ns) { w0 = z4; w1 = z4; w2 = z4; w3 = z4; ns = nxt(l); }
        w0 = w1; w1 = w2; w2 = w3; w3 = hw[i];
      }
    }
    auto convg = [&](int g, f32x4 (&p)[4]) {
      const int lb = l0 + 64 + r0 + g * 4;
      const int rl = r0 + g * 4;
      dorow((bf16*)As[1], lb + 0, w0, w1, w2, w3, p[0], rl + 0);
      dorow((bf16*)As[1], lb + 1, w1, w2, w3, p[0], p[1], rl + 1);
      dorow((bf16*)As[1], lb + 2, w2, w3, p[0], p[1], p[2], rl + 2);
      dorow((bf16*)As[1], lb + 3, w3, p[0], p[1], p[2], p[3], rl + 3);
      w0 = p[0]; w1 = p[1]; w2 = p[2]; w3 = p[3];
    };
    const bf16* A0 = (const bf16*)As[0];
    // superstep 0
    ldg1(1, pB);
    convg(0, pA);
    gemm_step(A0, 0); gemm_step(A0, 1); gemm_step(A0, 2); gemm_step(A0, 3);
    // superstep 1
    ldg1(2, pA);
    convg(1, pB);
    gemm_step(A0, 4); gemm_step(A0, 5); gemm_step(A0, 6); gemm_step(A0, 7);
    // superstep 2
    ldg1(3, pB);
    convg(2, pA);
    gemm_step(A0, 8); gemm_step(A0, 9); gemm_step(A0, 10); gemm_step(A0, 11);
    // superstep 3
    convg(3, pB);
    gemm_step(A0, 12); gemm_step(A0, 13); gemm_step(A0, 14); gemm_step(A0, 15);
  }

  epilogue(0);  // t0 stores drain under the barrier + t1 GEMM

  DSFLUSH_BARRIER;  // As[1] published

  // ================= P2: GEMM(t1) =================
#pragma unroll
  for (int i = 0; i < 4; ++i)
#pragma unroll
    for (int j = 0; j < 4; ++j) acc[i][j] = z4;
  {
    const bf16* A1 = (const bf16*)As[1];
#pragma unroll 1
    for (int kk = 0; kk < 16; ++kk) gemm_step(A1, kk);
  }
  epilogue(64);
}

extern "C" void kernel_launch(void* const* d_in, const int* in_sizes, int n_in,
                              void* d_out, int out_size, void* d_ws,
                              size_t ws_size, hipStream_t stream) {
  const float* x = (const float*)d_in[0];
  const int* segb = (const int*)d_in[1];      // [B][S][2] int32
  const float* w_dw = (const float*)d_in[2];  // [C][K]
  const float* b_dw = (const float*)d_in[3];  // [C]
  const float* w_pw = (const float*)d_in[4];  // [C_out][C_in]
  const float* b_pw = (const float*)d_in[5];  // [C]
  float* out = (float*)d_out;

  float* bias2 = (float*)d_ws;             // 4 KB
  bf16* pk = (bf16*)((char*)d_ws + 4096);  // 512 KB packed B

  prep_kernel<<<640, 256, 0, stream>>>(w_pw, b_dw, b_pw, pk, bias2);
  fused_kernel<<<NB * L_ / 128, 512, 0, stream>>>(x, segb, w_dw, pk, bias2,
                                                  out);
}